// Round 1
// baseline (1071.869 us; speedup 1.0000x reference)
//
#include <hip/hip_runtime.h>
#include <cmath>

// EntNet forward: T=4 scan steps over entity memory.
// Sizes fixed by the reference problem.
constexpr int T = 4, B = 64, L = 32, E = 1024, D = 256;
constexpr int ETILE = 32;

// ---------------------------------------------------------------------------
// h[t,b,d] = sum_{l < len[t,b]} embed[sent[t,b,l], d] * pos_w[l, d]
// grid = T*B blocks, D threads
__global__ void k_h(const float* __restrict__ embed, const float* __restrict__ pos_w,
                    const int* __restrict__ sentences, const int* __restrict__ lengths,
                    float* __restrict__ h) {
  int tb = blockIdx.x;            // t*B + b
  int d  = threadIdx.x;           // 0..D-1
  const int* sent = sentences + tb * L;
  int len = lengths[tb];          // in [4, L]
  float acc = 0.f;
  for (int l = 0; l < len; ++l) {
    int tok = sent[l];
    acc += embed[(size_t)tok * D + d] * pos_w[l * D + d];
  }
  h[(size_t)tb * D + d] = acc;
}

// ---------------------------------------------------------------------------
// oc[t,b,f] = sum_d h[t,b,d] * Wc[d,f]   (tiny matmul, grid = T*B blocks)
__global__ void k_oc(const float* __restrict__ h, const float* __restrict__ Wc,
                     float* __restrict__ oc) {
  int tb = blockIdx.x;
  int f  = threadIdx.x;
  __shared__ float hs[D];
  hs[f] = h[(size_t)tb * D + f];
  __syncthreads();
  float acc = 0.f;
  for (int d0 = 0; d0 < D; d0 += 4) {
    float4 hv = *(const float4*)&hs[d0];
    acc += hv.x * Wc[(d0 + 0) * D + f] + hv.y * Wc[(d0 + 1) * D + f]
         + hv.z * Wc[(d0 + 2) * D + f] + hv.w * Wc[(d0 + 3) * D + f];
  }
  oc[(size_t)tb * D + f] = acc;
}

// ---------------------------------------------------------------------------
// ksc[t,b,e] = keys[b,e,:] . h[t,b,:]  for all t in one pass over keys.
// block = 256 threads = 4 waves, one (b,e) row per wave.
__global__ void k_keyscore(const float* __restrict__ keys, const float* __restrict__ h,
                           float* __restrict__ ksc) {
  int row  = blockIdx.x * 4 + (threadIdx.x >> 6);  // b*E + e
  int lane = threadIdx.x & 63;
  int b = row >> 10;            // / E
  const float4* kp = (const float4*)(keys + (size_t)row * D);
  float4 kv = kp[lane];
  float acc[T];
#pragma unroll
  for (int t = 0; t < T; ++t) {
    const float4* hp = (const float4*)(h + ((size_t)t * B + b) * D);
    float4 hv = hp[lane];
    acc[t] = kv.x * hv.x + kv.y * hv.y + kv.z * hv.z + kv.w * hv.w;
  }
#pragma unroll
  for (int t = 0; t < T; ++t) {
#pragma unroll
    for (int off = 32; off >= 1; off >>= 1) acc[t] += __shfl_xor(acc[t], off, 64);
  }
  if (lane == 0) {
    int e = row & (E - 1);
#pragma unroll
    for (int t = 0; t < T; ++t)
      ksc[((size_t)t * B + b) * E + e] = acc[t];
  }
}

// ---------------------------------------------------------------------------
// Y[r, f] = sum_d X[r, d] * W[d, f]  for ETILE rows per block (fp32 VALU).
// Used for ok = keys @ Wk (computed once; scan-invariant).
__global__ __launch_bounds__(256) void k_rowmm(const float* __restrict__ X,
                                               const float* __restrict__ W,
                                               float* __restrict__ Y) {
  int r0 = blockIdx.x * ETILE;
  int f  = threadIdx.x;
  __shared__ float xs[ETILE][D];
  {
    const float4* src = (const float4*)(X + (size_t)r0 * D);
    float4* dst = (float4*)&xs[0][0];
#pragma unroll
    for (int c = 0; c < ETILE * D / 4 / 256; ++c)
      dst[c * 256 + f] = src[c * 256 + f];
  }
  __syncthreads();
  float acc[ETILE];
#pragma unroll
  for (int e = 0; e < ETILE; ++e) acc[e] = 0.f;
  for (int d0 = 0; d0 < D; d0 += 4) {
    float w0 = W[(d0 + 0) * D + f], w1 = W[(d0 + 1) * D + f],
          w2 = W[(d0 + 2) * D + f], w3 = W[(d0 + 3) * D + f];
#pragma unroll
    for (int e = 0; e < ETILE; ++e) {
      float4 xv = *(const float4*)&xs[e][d0];
      acc[e] += xv.x * w0 + xv.y * w1 + xv.z * w2 + xv.w * w3;
    }
  }
#pragma unroll
  for (int e = 0; e < ETILE; ++e)
    Y[((size_t)r0 + e) * D + f] = acc[e];
}

// ---------------------------------------------------------------------------
// Fused per-step update: dist, oe (=ents@Wv, + keys@Wk if !HAS_OK), gated
// PReLU update, L2 renorm, write-out, and (LAST) joint accumulation.
// grid = (E/ETILE, B), 256 threads.
template <bool HAS_OK, bool LAST>
__global__ __launch_bounds__(256) void k_update(
    const float* __restrict__ ents_in,
    const float* __restrict__ okp,       // precomputed keys@Wk  (HAS_OK)
    const float* __restrict__ keys,      // used when !HAS_OK
    const float* __restrict__ Wk,        // used when !HAS_OK
    const float* __restrict__ Wv,
    const float* __restrict__ h_t,       // [B][D]
    const float* __restrict__ oc_t,      // [B][D]
    const float* __restrict__ ksc_t,     // [B][E]
    const float* __restrict__ prelu_w,   // [D]
    float* __restrict__ ents_out,
    float* __restrict__ joint)           // [B][D], LAST only
{
  int b   = blockIdx.y;
  int e0  = blockIdx.x * ETILE;
  int tid = threadIdx.x;
  int w = tid >> 6, lane = tid & 63;

  __shared__ float es[ETILE][D];                 // 32 KB
  __shared__ float hs[D];
  __shared__ float dist_s[ETILE];
  __shared__ float inorm_s[ETILE];
  __shared__ float ks[(HAS_OK ? 1 : ETILE * D)]; // keys tile only if fused ok

  const size_t rowbase = ((size_t)b * E + e0) * D;
  {
    const float4* src = (const float4*)(ents_in + rowbase);
    float4* dst = (float4*)&es[0][0];
#pragma unroll
    for (int c = 0; c < 8; ++c) dst[c * 256 + tid] = src[c * 256 + tid];
    if (!HAS_OK) {
      const float4* ksrc = (const float4*)(keys + rowbase);
      float4* kdst = (float4*)&ks[0];
#pragma unroll
      for (int c = 0; c < 8; ++c) kdst[c * 256 + tid] = ksrc[c * 256 + tid];
    }
    hs[tid] = h_t[b * D + tid];
  }
  __syncthreads();

  // ---- dist = sigmoid(ents.h + ksc) : 8 rows per wave, shuffle reduce
  {
    float4 hv = ((const float4*)hs)[lane];
#pragma unroll
    for (int r = 0; r < ETILE / 4; ++r) {
      int e = w * (ETILE / 4) + r;
      float4 ev = ((const float4*)&es[e][0])[lane];
      float a = ev.x * hv.x + ev.y * hv.y + ev.z * hv.z + ev.w * hv.w;
#pragma unroll
      for (int off = 32; off >= 1; off >>= 1) a += __shfl_xor(a, off, 64);
      if (lane == 0) {
        float s = a + ksc_t[(size_t)b * E + e0 + e];
        dist_s[e] = 1.f / (1.f + expf(-s));
      }
    }
  }

  // ---- oe[e][f] = sum_d es[e][d] * Wv[d][f]  (+ keys@Wk fused if !HAS_OK)
  float acc[ETILE];
#pragma unroll
  for (int e = 0; e < ETILE; ++e) acc[e] = 0.f;
  for (int d0 = 0; d0 < D; d0 += 4) {
    float w0 = Wv[(d0 + 0) * D + tid], w1 = Wv[(d0 + 1) * D + tid],
          w2 = Wv[(d0 + 2) * D + tid], w3 = Wv[(d0 + 3) * D + tid];
    float u0, u1, u2, u3;
    if (!HAS_OK) {
      u0 = Wk[(d0 + 0) * D + tid]; u1 = Wk[(d0 + 1) * D + tid];
      u2 = Wk[(d0 + 2) * D + tid]; u3 = Wk[(d0 + 3) * D + tid];
    }
#pragma unroll
    for (int e = 0; e < ETILE; ++e) {
      float4 xv = *(const float4*)&es[e][d0];
      acc[e] += xv.x * w0 + xv.y * w1 + xv.z * w2 + xv.w * w3;
      if (!HAS_OK) {
        float4 kv = *(const float4*)&ks[e * D + d0];
        acc[e] += kv.x * u0 + kv.y * u1 + kv.z * u2 + kv.w * u3;
      }
    }
  }
  __syncthreads();  // all es reads done; dist_s visible to all

  // ---- gated PReLU update (in place in LDS; each thread touches es[e][tid])
  float ocv = oc_t[b * D + tid];
  float pw  = prelu_w[tid];
#pragma unroll
  for (int e = 0; e < ETILE; ++e) {
    float pre = acc[e] + ocv;
    if (HAS_OK) pre += okp[rowbase + (size_t)e * D + tid];
    float de = dist_s[e];
    float pr = pre >= 0.f ? pre : pw * pre;
    float nv = de * pr + (1.f - de) * es[e][tid];
    es[e][tid] = nv;
  }
  __syncthreads();

  // ---- 1/||new|| per row
#pragma unroll
  for (int r = 0; r < ETILE / 4; ++r) {
    int e = w * (ETILE / 4) + r;
    float4 v = ((const float4*)&es[e][0])[lane];
    float s = v.x * v.x + v.y * v.y + v.z * v.z + v.w * v.w;
#pragma unroll
    for (int off = 32; off >= 1; off >>= 1) s += __shfl_xor(s, off, 64);
    if (lane == 0) inorm_s[e] = 1.f / sqrtf(s);
  }
  __syncthreads();

  // ---- write out (+ joint partial)
  float jacc = 0.f;
#pragma unroll
  for (int e = 0; e < ETILE; ++e) {
    float outv = es[e][tid] * inorm_s[e];
    ents_out[rowbase + (size_t)e * D + tid] = outv;
    if (LAST) jacc += dist_s[e] * outv;
  }
  if (LAST) atomicAdd(&joint[b * D + tid], jacc);
}

// ---------------------------------------------------------------------------
extern "C" void kernel_launch(void* const* d_in, const int* in_sizes, int n_in,
                              void* d_out, int out_size, void* d_ws, size_t ws_size,
                              hipStream_t stream) {
  const float* embed    = (const float*)d_in[0];
  const float* pos_w    = (const float*)d_in[1];
  const float* keys     = (const float*)d_in[2];
  const float* entities = (const float*)d_in[3];
  const float* Wk       = (const float*)d_in[4];
  const float* Wv       = (const float*)d_in[5];
  const float* Wc       = (const float*)d_in[6];
  const float* prelu_w  = (const float*)d_in[7];
  const int* sentences  = (const int*)d_in[8];
  const int* lengths    = (const int*)d_in[9];

  float* out_ents  = (float*)d_out;                      // [B*E*D]
  float* out_joint = out_ents + (size_t)B * E * D;       // [B*D]

  float* h        = (float*)d_ws;                        // T*B*D
  float* oc       = h + (size_t)T * B * D;               // T*B*D
  float* ksc      = oc + (size_t)T * B * D;              // T*B*E
  float* ents_buf = ksc + (size_t)T * B * E;             // B*E*D
  float* ok       = ents_buf + (size_t)B * E * D;        // B*E*D (optional)

  size_t need_full = ((size_t)T * B * D * 2 + (size_t)T * B * E +
                      (size_t)B * E * D * 2) * sizeof(float);
  bool has_ok = ws_size >= need_full;

  hipMemsetAsync(out_joint, 0, (size_t)B * D * sizeof(float), stream);

  k_h<<<T * B, D, 0, stream>>>(embed, pos_w, sentences, lengths, h);
  k_oc<<<T * B, D, 0, stream>>>(h, Wc, oc);
  k_keyscore<<<B * E / 4, 256, 0, stream>>>(keys, h, ksc);
  if (has_ok) k_rowmm<<<B * E / ETILE, 256, 0, stream>>>(keys, Wk, ok);

  const float* in_p[T]  = { entities, ents_buf, out_ents, ents_buf };
  float*       out_p[T] = { ents_buf, out_ents, ents_buf, out_ents };

  for (int t = 0; t < T; ++t) {
    const float* h_t   = h   + (size_t)t * B * D;
    const float* oc_t  = oc  + (size_t)t * B * D;
    const float* ksc_t = ksc + (size_t)t * B * E;
    dim3 grid(E / ETILE, B);
    bool last = (t == T - 1);
    if (has_ok) {
      if (last)
        k_update<true, true><<<grid, 256, 0, stream>>>(in_p[t], ok, keys, Wk, Wv,
            h_t, oc_t, ksc_t, prelu_w, out_p[t], out_joint);
      else
        k_update<true, false><<<grid, 256, 0, stream>>>(in_p[t], ok, keys, Wk, Wv,
            h_t, oc_t, ksc_t, prelu_w, out_p[t], out_joint);
    } else {
      if (last)
        k_update<false, true><<<grid, 256, 0, stream>>>(in_p[t], nullptr, keys, Wk, Wv,
            h_t, oc_t, ksc_t, prelu_w, out_p[t], out_joint);
      else
        k_update<false, false><<<grid, 256, 0, stream>>>(in_p[t], nullptr, keys, Wk, Wv,
            h_t, oc_t, ksc_t, prelu_w, out_p[t], out_joint);
    }
  }
  (void)in_sizes; (void)n_in; (void)out_size;
}

// Round 5
// 426.266 us; speedup vs baseline: 2.5146x; 2.5146x over previous
//
#include <hip/hip_runtime.h>
#include <cmath>

// EntNet forward, MFMA version. T=4 scan steps over entity memory.
constexpr int T = 4, B = 64, L = 32, E = 1024, D = 256;
constexpr int MT = 32;               // entity rows per block

typedef __attribute__((ext_vector_type(8))) short short8;
typedef __attribute__((ext_vector_type(4))) float f32x4;
typedef __attribute__((ext_vector_type(4))) unsigned short u16x4;

static __device__ __forceinline__ unsigned short f2bf(float x) {
  unsigned int u = __builtin_bit_cast(unsigned int, x);
  unsigned int r = u + 0x7fffu + ((u >> 16) & 1u);   // RNE
  return (unsigned short)(r >> 16);
}
static __device__ __forceinline__ float bf2f(unsigned short s) {
  unsigned int u = ((unsigned int)s) << 16;
  return __builtin_bit_cast(float, u);
}

// ---------------------------------------------------------------------------
// h[t,b,d] = sum_{l < len[t,b]} embed[sent[t,b,l], d] * pos_w[l, d]
__global__ void k_h(const float* __restrict__ embed, const float* __restrict__ pos_w,
                    const int* __restrict__ sentences, const int* __restrict__ lengths,
                    float* __restrict__ h) {
  int tb = blockIdx.x;
  int d  = threadIdx.x;
  const int* sent = sentences + tb * L;
  int len = lengths[tb];
  float acc = 0.f;
  for (int l = 0; l < len; ++l) {
    int tok = sent[l];
    acc += embed[(size_t)tok * D + d] * pos_w[l * D + d];
  }
  h[(size_t)tb * D + d] = acc;
}

// ---------------------------------------------------------------------------
// oc[t,b,f] = sum_d h[t,b,d] * Wc[d,f]
__global__ void k_oc(const float* __restrict__ h, const float* __restrict__ Wc,
                     float* __restrict__ oc) {
  int tb = blockIdx.x;
  int f  = threadIdx.x;
  __shared__ float hs[D];
  hs[f] = h[(size_t)tb * D + f];
  __syncthreads();
  float acc = 0.f;
  for (int d0 = 0; d0 < D; d0 += 4) {
    float4 hv = *(const float4*)&hs[d0];
    acc += hv.x * Wc[(d0 + 0) * D + f] + hv.y * Wc[(d0 + 1) * D + f]
         + hv.z * Wc[(d0 + 2) * D + f] + hv.w * Wc[(d0 + 3) * D + f];
  }
  oc[(size_t)tb * D + f] = acc;
}

// ---------------------------------------------------------------------------
// ksc[t,b,e] = keys[b,e,:] . h[t,b,:]  (fp32, one pass over keys)
__global__ void k_keyscore(const float* __restrict__ keys, const float* __restrict__ h,
                           float* __restrict__ ksc) {
  int row  = blockIdx.x * 4 + (threadIdx.x >> 6);
  int lane = threadIdx.x & 63;
  int b = row >> 10;
  const float4* kp = (const float4*)(keys + (size_t)row * D);
  float4 kv = kp[lane];
  float acc[T];
#pragma unroll
  for (int t = 0; t < T; ++t) {
    const float4* hp = (const float4*)(h + ((size_t)t * B + b) * D);
    float4 hv = hp[lane];
    acc[t] = kv.x * hv.x + kv.y * hv.y + kv.z * hv.z + kv.w * hv.w;
  }
#pragma unroll
  for (int t = 0; t < T; ++t) {
#pragma unroll
    for (int off = 32; off >= 1; off >>= 1) acc[t] += __shfl_xor(acc[t], off, 64);
  }
  if (lane == 0) {
    int e = row & (E - 1);
#pragma unroll
    for (int t = 0; t < T; ++t)
      ksc[((size_t)t * B + b) * E + e] = acc[t];
  }
}

// ---------------------------------------------------------------------------
// WT[n][k] = bf16( (k<256 ? Wv : Wk)[k&255][n] )   — combined B^T, [256][512]
__global__ void k_wt(const float* __restrict__ Wv, const float* __restrict__ Wk,
                     unsigned short* __restrict__ WT) {
  int n = blockIdx.x, k = threadIdx.x;
  WT[(size_t)n * 512 + k]       = f2bf(Wv[(size_t)k * D + n]);
  WT[(size_t)n * 512 + 256 + k] = f2bf(Wk[(size_t)k * D + n]);
}

// keysb = bf16(keys), flat
__global__ void k_keysb(const float* __restrict__ keys, unsigned short* __restrict__ kb,
                        int n4) {
  int i = blockIdx.x * blockDim.x + threadIdx.x;
  int stride = gridDim.x * blockDim.x;
  for (; i < n4; i += stride) {
    float4 v = ((const float4*)keys)[i];
    u16x4 o;
    o[0] = f2bf(v.x); o[1] = f2bf(v.y); o[2] = f2bf(v.z); o[3] = f2bf(v.w);
    ((u16x4*)kb)[i] = o;
  }
}

// ---------------------------------------------------------------------------
// Fused step: dist = sigmoid(ents.h + ksc); pre = [ents,keys]@[Wv;Wk] + oc;
// new = dist*prelu(pre) + (1-dist)*ents; renorm; (+ joint on LAST).
// grid (E/MT, B), 256 threads = 4 waves. Wave w owns cols [w*64, w*64+64).
template <bool IN_F32, bool KEYS_BF, bool LAST>
__global__ __launch_bounds__(256) void k_update(
    const float* __restrict__ ents_f32,
    const unsigned short* __restrict__ ents_bf,
    const unsigned short* __restrict__ keysb,
    const float* __restrict__ keysf,
    const unsigned short* __restrict__ WT,
    const float* __restrict__ h_t,
    const float* __restrict__ oc_t,
    const float* __restrict__ ksc_t,
    const float* __restrict__ prelu_w,
    unsigned short* __restrict__ ents_out_bf,
    float* __restrict__ ents_out_f32,
    float* __restrict__ joint) {
  int b = blockIdx.y, e0 = blockIdx.x * MT;
  int tid = threadIdx.x;

  // LDS: A-tile [32 rows][512 k] bf16, XOR-swizzled (u16-idx ^= (row&7)<<3)
  __shared__ unsigned short es[MT * 512];       // 32 KB
  __shared__ float hs[D], ocs[D], pws[D];
  __shared__ float dist_s[MT], rowsum[4][MT], inv_s[MT];

  hs[tid]  = h_t[(size_t)b * D + tid];
  ocs[tid] = oc_t[(size_t)b * D + tid];
  pws[tid] = prelu_w[tid];
  __syncthreads();

  // ---- load tile: row r = tid>>3, 64 cols starting at (tid&7)*64.
  // cols 0..255 = ents (dot with h for dist), 256..511 = keys (bf16).
  {
    int r = tid >> 3, cs = (tid & 7) * 64;
    size_t rowbase = ((size_t)b * E + e0 + r) * D;
    unsigned short tmp[64];
    float partial = 0.f;
    if (cs < 256) {
      if (IN_F32) {
        const float4* src = (const float4*)(ents_f32 + rowbase + cs);
#pragma unroll
        for (int q = 0; q < 16; ++q) {
          float4 v = src[q];
          int c = cs + q * 4;
          partial += v.x * hs[c] + v.y * hs[c + 1] + v.z * hs[c + 2] + v.w * hs[c + 3];
          tmp[q * 4 + 0] = f2bf(v.x); tmp[q * 4 + 1] = f2bf(v.y);
          tmp[q * 4 + 2] = f2bf(v.z); tmp[q * 4 + 3] = f2bf(v.w);
        }
      } else {
        const short8* src = (const short8*)(ents_bf + rowbase + cs);
#pragma unroll
        for (int q = 0; q < 8; ++q) {
          short8 v = src[q];
#pragma unroll
          for (int j = 0; j < 8; ++j) {
            float f = bf2f((unsigned short)v[j]);
            partial += f * hs[cs + q * 8 + j];
            tmp[q * 8 + j] = (unsigned short)v[j];
          }
        }
      }
    } else {
      int kc = cs - 256;
      size_t kbase = ((size_t)b * E + e0 + r) * D + kc;
      if (KEYS_BF) {
        const short8* src = (const short8*)(keysb + kbase);
#pragma unroll
        for (int q = 0; q < 8; ++q) {
          short8 v = src[q];
          *(short8*)&tmp[q * 8] = v;
        }
      } else {
        const float4* src = (const float4*)(keysf + kbase);
#pragma unroll
        for (int q = 0; q < 16; ++q) {
          float4 v = src[q];
          tmp[q * 4 + 0] = f2bf(v.x); tmp[q * 4 + 1] = f2bf(v.y);
          tmp[q * 4 + 2] = f2bf(v.z); tmp[q * 4 + 3] = f2bf(v.w);
        }
      }
    }
#pragma unroll
    for (int q = 0; q < 8; ++q) {
      int idx = (r * 512 + cs + q * 8) ^ ((r & 7) << 3);
      *(short8*)&es[idx] = *(const short8*)&tmp[q * 8];
    }
    partial += __shfl_xor(partial, 1);
    partial += __shfl_xor(partial, 2);
    partial += __shfl_xor(partial, 4);
    if ((tid & 7) == 0) {
      float s = partial + ksc_t[(size_t)b * E + e0 + r];
      dist_s[r] = 1.f / (1.f + expf(-s));
    }
  }
  __syncthreads();

  // ---- MFMA: acc[rt][ct] = A(32x512) @ B(512x256), wave's 64-col strip.
  int lane = tid & 63, w = tid >> 6;
  int col16 = lane & 15, kg = lane >> 4;
  f32x4 acc[2][4];
#pragma unroll
  for (int rt = 0; rt < 2; ++rt)
#pragma unroll
    for (int ct = 0; ct < 4; ++ct) acc[rt][ct] = (f32x4)(0.f);

  const int kofs = kg * 8;
#pragma unroll 4
  for (int kb = 0; kb < 16; ++kb) {
    int k0 = kb * 32 + kofs;
    short8 a0 = *(const short8*)&es[((col16) * 512 + k0) ^ ((col16 & 7) << 3)];
    short8 a1 = *(const short8*)&es[((col16 + 16) * 512 + k0) ^ ((col16 & 7) << 3)];
    short8 bv[4];
#pragma unroll
    for (int ct = 0; ct < 4; ++ct) {
      int n = w * 64 + ct * 16 + col16;
      bv[ct] = *(const short8*)&WT[(size_t)n * 512 + k0];
    }
#pragma unroll
    for (int ct = 0; ct < 4; ++ct) {
      acc[0][ct] = __builtin_amdgcn_mfma_f32_16x16x32_bf16(a0, bv[ct], acc[0][ct], 0, 0, 0);
      acc[1][ct] = __builtin_amdgcn_mfma_f32_16x16x32_bf16(a1, bv[ct], acc[1][ct], 0, 0, 0);
    }
  }

  // ---- epilogue: gated PReLU blend (in registers, D layout: row=(kg*4+r), col=col16)
#pragma unroll
  for (int rt = 0; rt < 2; ++rt)
#pragma unroll
    for (int ct = 0; ct < 4; ++ct) {
      int n = w * 64 + ct * 16 + col16;
      float ocv = ocs[n], pwv = pws[n];
#pragma unroll
      for (int r = 0; r < 4; ++r) {
        int m = rt * 16 + kg * 4 + r;
        float pre = acc[rt][ct][r] + ocv;
        float pr = pre >= 0.f ? pre : pwv * pre;
        float de = dist_s[m];
        float esv = bf2f(es[(m * 512 + n) ^ ((m & 7) << 3)]);
        acc[rt][ct][r] = de * pr + (1.f - de) * esv;
      }
    }

  // ---- row sum-of-squares: reduce 16 cols in-wave, then 4 waves via LDS
#pragma unroll
  for (int rt = 0; rt < 2; ++rt)
#pragma unroll
    for (int r = 0; r < 4; ++r) {
      float s = acc[rt][0][r] * acc[rt][0][r] + acc[rt][1][r] * acc[rt][1][r]
              + acc[rt][2][r] * acc[rt][2][r] + acc[rt][3][r] * acc[rt][3][r];
      s += __shfl_xor(s, 1); s += __shfl_xor(s, 2);
      s += __shfl_xor(s, 4); s += __shfl_xor(s, 8);
      if (col16 == 0) rowsum[w][rt * 16 + kg * 4 + r] = s;
    }
  __syncthreads();
  if (tid < MT)
    inv_s[tid] = rsqrtf(rowsum[0][tid] + rowsum[1][tid] + rowsum[2][tid] + rowsum[3][tid]);
  __syncthreads();

  // ---- scale + store (+ joint on LAST)
  size_t obase = ((size_t)b * E + e0) * D;
  float jacc[4] = {0.f, 0.f, 0.f, 0.f};
#pragma unroll
  for (int rt = 0; rt < 2; ++rt)
#pragma unroll
    for (int ct = 0; ct < 4; ++ct) {
      int n = w * 64 + ct * 16 + col16;
#pragma unroll
      for (int r = 0; r < 4; ++r) {
        int m = rt * 16 + kg * 4 + r;
        float val = acc[rt][ct][r] * inv_s[m];
        if (LAST) {
          ents_out_f32[obase + (size_t)m * D + n] = val;
          jacc[ct] += dist_s[m] * val;
        } else {
          ents_out_bf[obase + (size_t)m * D + n] = f2bf(val);
        }
      }
    }
  if (LAST) {
#pragma unroll
    for (int ct = 0; ct < 4; ++ct) {
      float s = jacc[ct];
      s += __shfl_xor(s, 16);
      s += __shfl_xor(s, 32);
      if (kg == 0) atomicAdd(&joint[(size_t)b * D + w * 64 + ct * 16 + col16], s);
    }
  }
}

// ---------------------------------------------------------------------------
extern "C" void kernel_launch(void* const* d_in, const int* in_sizes, int n_in,
                              void* d_out, int out_size, void* d_ws, size_t ws_size,
                              hipStream_t stream) {
  const float* embed    = (const float*)d_in[0];
  const float* pos_w    = (const float*)d_in[1];
  const float* keys     = (const float*)d_in[2];
  const float* entities = (const float*)d_in[3];
  const float* Wk       = (const float*)d_in[4];
  const float* Wv       = (const float*)d_in[5];
  const float* Wc       = (const float*)d_in[6];
  const float* prelu_w  = (const float*)d_in[7];
  const int* sentences  = (const int*)d_in[8];
  const int* lengths    = (const int*)d_in[9];

  float* out_ents  = (float*)d_out;
  float* out_joint = out_ents + (size_t)B * E * D;

  // ws layout
  float* h   = (float*)d_ws;                              // T*B*D
  float* oc  = h + (size_t)T * B * D;                     // T*B*D
  float* ksc = oc + (size_t)T * B * D;                    // T*B*E
  unsigned short* WT    = (unsigned short*)(ksc + (size_t)T * B * E);  // 256*512
  unsigned short* ents0 = WT + (size_t)256 * 512;         // B*E*D bf16
  unsigned short* ents1 = ents0 + (size_t)B * E * D;      // B*E*D bf16
  unsigned short* keysb = ents1 + (size_t)B * E * D;      // B*E*D bf16 (optional)

  size_t base_b = ((size_t)T * B * D * 2 + (size_t)T * B * E) * 4 + (size_t)256 * 512 * 2
                + 2 * (size_t)B * E * D * 2;
  bool use_kb = ws_size >= base_b + (size_t)B * E * D * 2;

  hipMemsetAsync(out_joint, 0, (size_t)B * D * sizeof(float), stream);

  k_h<<<T * B, D, 0, stream>>>(embed, pos_w, sentences, lengths, h);
  k_oc<<<T * B, D, 0, stream>>>(h, Wc, oc);
  k_keyscore<<<B * E / 4, 256, 0, stream>>>(keys, h, ksc);
  k_wt<<<256, 256, 0, stream>>>(Wv, Wk, WT);
  if (use_kb) k_keysb<<<2048, 256, 0, stream>>>(keys, keysb, B * E * D / 4);

  dim3 grid(E / MT, B);
  const unsigned short* in_bf[T] = { nullptr, ents0, ents1, ents0 };
  unsigned short*      out_bf[T] = { ents0, ents1, ents0, nullptr };

  for (int t = 0; t < T; ++t) {
    const float* h_t   = h   + (size_t)t * B * D;
    const float* oc_t  = oc  + (size_t)t * B * D;
    const float* ksc_t = ksc + (size_t)t * B * E;
    bool last = (t == T - 1);
    if (use_kb) {
      if (t == 0)
        k_update<true, true, false><<<grid, 256, 0, stream>>>(entities, nullptr, keysb, keys,
            WT, h_t, oc_t, ksc_t, prelu_w, out_bf[t], nullptr, nullptr);
      else if (!last)
        k_update<false, true, false><<<grid, 256, 0, stream>>>(nullptr, in_bf[t], keysb, keys,
            WT, h_t, oc_t, ksc_t, prelu_w, out_bf[t], nullptr, nullptr);
      else
        k_update<false, true, true><<<grid, 256, 0, stream>>>(nullptr, in_bf[t], keysb, keys,
            WT, h_t, oc_t, ksc_t, prelu_w, nullptr, out_ents, out_joint);
    } else {
      if (t == 0)
        k_update<true, false, false><<<grid, 256, 0, stream>>>(entities, nullptr, nullptr, keys,
            WT, h_t, oc_t, ksc_t, prelu_w, out_bf[t], nullptr, nullptr);
      else if (!last)
        k_update<false, false, false><<<grid, 256, 0, stream>>>(nullptr, in_bf[t], nullptr, keys,
            WT, h_t, oc_t, ksc_t, prelu_w, out_bf[t], nullptr, nullptr);
      else
        k_update<false, false, true><<<grid, 256, 0, stream>>>(nullptr, in_bf[t], nullptr, keys,
            WT, h_t, oc_t, ksc_t, prelu_w, nullptr, out_ents, out_joint);
    }
  }
  (void)in_sizes; (void)n_in; (void)out_size;
}

// Round 6
// 277.467 us; speedup vs baseline: 3.8631x; 1.5363x over previous
//
#include <hip/hip_runtime.h>
#include <cmath>

// EntNet forward, MFMA v2. keys@Wk precomputed once (scan-invariant);
// per-step GEMM is ents@Wv (K=256) with fragment-layout B and okb.
constexpr int T = 4, B = 64, L = 32, E = 1024, D = 256;
constexpr int MT = 64;            // entity rows per block
constexpr int NBLK = E / MT;      // 16

typedef __attribute__((ext_vector_type(8))) short short8;
typedef __attribute__((ext_vector_type(4))) float f32x4;
typedef __attribute__((ext_vector_type(4))) unsigned short u16x4;

static __device__ __forceinline__ unsigned short f2bf(float x) {
  unsigned int u = __builtin_bit_cast(unsigned int, x);
  unsigned int r = u + 0x7fffu + ((u >> 16) & 1u);   // RNE
  return (unsigned short)(r >> 16);
}
static __device__ __forceinline__ float bf2f(unsigned short s) {
  unsigned int u = ((unsigned int)s) << 16;
  return __builtin_bit_cast(float, u);
}

// ---------------------------------------------------------------------------
// h[t,b,d] = sum_{l < len[t,b]} embed[sent[t,b,l], d] * pos_w[l, d]
__global__ void k_h(const float* __restrict__ embed, const float* __restrict__ pos_w,
                    const int* __restrict__ sentences, const int* __restrict__ lengths,
                    float* __restrict__ h) {
  int tb = blockIdx.x;
  int d  = threadIdx.x;
  const int* sent = sentences + tb * L;
  int len = lengths[tb];
  float acc = 0.f;
  for (int l = 0; l < len; ++l) {
    int tok = sent[l];
    acc += embed[(size_t)tok * D + d] * pos_w[l * D + d];
  }
  h[(size_t)tb * D + d] = acc;
}

// ---------------------------------------------------------------------------
// oc[t,b,f] = sum_d h[t,b,d] * Wc[d,f]
__global__ void k_oc(const float* __restrict__ h, const float* __restrict__ Wc,
                     float* __restrict__ oc) {
  int tb = blockIdx.x;
  int f  = threadIdx.x;
  __shared__ float hs[D];
  hs[f] = h[(size_t)tb * D + f];
  __syncthreads();
  float acc = 0.f;
  for (int d0 = 0; d0 < D; d0 += 4) {
    float4 hv = *(const float4*)&hs[d0];
    acc += hv.x * Wc[(d0 + 0) * D + f] + hv.y * Wc[(d0 + 1) * D + f]
         + hv.z * Wc[(d0 + 2) * D + f] + hv.w * Wc[(d0 + 3) * D + f];
  }
  oc[(size_t)tb * D + f] = acc;
}

// ---------------------------------------------------------------------------
// Fragment-layout weights: for (n,k): idx = (((n>>4)*8 + (k>>5))*64 +
// ((k>>3)&3)*16 + (n&15))*8 + (k&7). One b128 per (ct,kb) per wave, coalesced.
__global__ void k_wt(const float* __restrict__ Wv, const float* __restrict__ Wk,
                     unsigned short* __restrict__ Wvfrag,
                     unsigned short* __restrict__ Wkfrag) {
  int n = blockIdx.x, k = threadIdx.x;
  int idx = (((n >> 4) * 8 + (k >> 5)) * 64 + ((k >> 3) & 3) * 16 + (n & 15)) * 8 + (k & 7);
  Wvfrag[idx] = f2bf(Wv[(size_t)k * D + n]);
  Wkfrag[idx] = f2bf(Wk[(size_t)k * D + n]);
}

// ---------------------------------------------------------------------------
// Precompute: okb = bf16(keys @ Wk) in MFMA C-fragment layout, and
// ksc[t,b,e] = keys[b,e,:].h[t,b,:] for all 4 t. One pass over f32 keys.
__global__ __launch_bounds__(256) void k_pre(
    const float* __restrict__ keys, const float* __restrict__ h,
    const unsigned short* __restrict__ Wkfrag,
    unsigned short* __restrict__ okb, float* __restrict__ ksc) {
  int b = blockIdx.y, e0 = blockIdx.x * MT;
  int blk = b * NBLK + blockIdx.x;
  int tid = threadIdx.x;

  __shared__ unsigned short es[MT * D];     // 32 KB, swizzled
  __shared__ float hs4[T][D];

#pragma unroll
  for (int t = 0; t < T; ++t) hs4[t][tid] = h[((size_t)t * B + b) * D + tid];
  __syncthreads();

  {
    int r = tid >> 2, c0 = (tid & 3) * 64;
    const float4* src = (const float4*)(keys + ((size_t)b * E + e0 + r) * D + c0);
    float p[T] = {0.f, 0.f, 0.f, 0.f};
    unsigned short tmp[64];
#pragma unroll
    for (int q = 0; q < 16; ++q) {
      float4 v = src[q];
      int c = c0 + q * 4;
#pragma unroll
      for (int t = 0; t < T; ++t)
        p[t] += v.x * hs4[t][c] + v.y * hs4[t][c + 1] + v.z * hs4[t][c + 2] + v.w * hs4[t][c + 3];
      tmp[q * 4 + 0] = f2bf(v.x); tmp[q * 4 + 1] = f2bf(v.y);
      tmp[q * 4 + 2] = f2bf(v.z); tmp[q * 4 + 3] = f2bf(v.w);
    }
#pragma unroll
    for (int q = 0; q < 8; ++q) {
      int idx = (r * D + c0 + q * 8) ^ ((r & 7) << 3);
      *(short8*)&es[idx] = *(const short8*)&tmp[q * 8];
    }
#pragma unroll
    for (int t = 0; t < T; ++t) {
      p[t] += __shfl_xor(p[t], 1);
      p[t] += __shfl_xor(p[t], 2);
    }
    if ((tid & 3) == 0) {
#pragma unroll
      for (int t = 0; t < T; ++t)
        ksc[((size_t)t * B + b) * E + e0 + r] = p[t];
    }
  }
  __syncthreads();

  int lane = tid & 63, w = tid >> 6;
  int col16 = lane & 15, kg = lane >> 4;
  const int swz = (col16 & 7) << 3;
  f32x4 acc[4][4];
#pragma unroll
  for (int rt = 0; rt < 4; ++rt)
#pragma unroll
    for (int ct = 0; ct < 4; ++ct) acc[rt][ct] = (f32x4)(0.f);

#pragma unroll 2
  for (int kb = 0; kb < 8; ++kb) {
    int k0 = kb * 32 + kg * 8;
    short8 a[4];
#pragma unroll
    for (int rt = 0; rt < 4; ++rt)
      a[rt] = *(const short8*)&es[((rt * 16 + col16) * D + k0) ^ swz];
    short8 bv[4];
#pragma unroll
    for (int ct = 0; ct < 4; ++ct)
      bv[ct] = *(const short8*)&Wkfrag[(size_t)(((w * 4 + ct) * 8 + kb) * 64 + lane) * 8];
#pragma unroll
    for (int rt = 0; rt < 4; ++rt)
#pragma unroll
      for (int ct = 0; ct < 4; ++ct)
        acc[rt][ct] = __builtin_amdgcn_mfma_f32_16x16x32_bf16(a[rt], bv[ct], acc[rt][ct], 0, 0, 0);
  }

#pragma unroll
  for (int rt = 0; rt < 4; ++rt)
#pragma unroll
    for (int ct = 0; ct < 4; ++ct) {
      u16x4 o;
#pragma unroll
      for (int r = 0; r < 4; ++r) o[r] = f2bf(acc[rt][ct][r]);
      *(u16x4*)&okb[((((size_t)blk * 4 + w) * 4 + rt) * 4 + ct) * 256 + lane * 4] = o;
    }
}

// ---------------------------------------------------------------------------
// Per-step: dist = sigmoid(ents.h + ksc); pre = ents@Wv + okb + oc;
// new = dist*prelu(pre) + (1-dist)*ents; L2 renorm; (+ joint on LAST).
// grid (NBLK, B), 256 threads = 4 waves; wave w owns cols [w*64, w*64+64).
template <bool IN_F32, bool LAST>
__global__ __launch_bounds__(256) void k_step(
    const float* __restrict__ ents_f32,
    const unsigned short* __restrict__ ents_bf,
    const unsigned short* __restrict__ Wvfrag,
    const unsigned short* __restrict__ okb,
    const float* __restrict__ h_t,
    const float* __restrict__ oc_t,
    const float* __restrict__ ksc_t,
    const float* __restrict__ prelu_w,
    unsigned short* __restrict__ out_bf,
    float* __restrict__ out_f32,
    float* __restrict__ joint) {
  int b = blockIdx.y, e0 = blockIdx.x * MT;
  int blk = b * NBLK + blockIdx.x;
  int tid = threadIdx.x;

  __shared__ unsigned short es[MT * D];     // 32 KB, swizzled
  __shared__ float hs[D], ocs[D], pws[D];
  __shared__ float dist_s[MT], rowsum[4][MT], inv_s[MT];

  hs[tid]  = h_t[(size_t)b * D + tid];
  ocs[tid] = oc_t[(size_t)b * D + tid];
  pws[tid] = prelu_w[tid];
  __syncthreads();

  // ---- stage ents tile (row r, 64-col chunk) + dist dot partial
  {
    int r = tid >> 2, c0 = (tid & 3) * 64;
    size_t base = ((size_t)b * E + e0 + r) * D + c0;
    unsigned short tmp[64];
    float p = 0.f;
    if (IN_F32) {
      const float4* src = (const float4*)(ents_f32 + base);
#pragma unroll
      for (int q = 0; q < 16; ++q) {
        float4 v = src[q];
        int c = c0 + q * 4;
        p += v.x * hs[c] + v.y * hs[c + 1] + v.z * hs[c + 2] + v.w * hs[c + 3];
        tmp[q * 4 + 0] = f2bf(v.x); tmp[q * 4 + 1] = f2bf(v.y);
        tmp[q * 4 + 2] = f2bf(v.z); tmp[q * 4 + 3] = f2bf(v.w);
      }
    } else {
      const short8* src = (const short8*)(ents_bf + base);
#pragma unroll
      for (int q = 0; q < 8; ++q) {
        short8 v = src[q];
#pragma unroll
        for (int j = 0; j < 8; ++j) {
          float f = bf2f((unsigned short)v[j]);
          p += f * hs[c0 + q * 8 + j];
          tmp[q * 8 + j] = (unsigned short)v[j];
        }
      }
    }
#pragma unroll
    for (int q = 0; q < 8; ++q) {
      int idx = (r * D + c0 + q * 8) ^ ((r & 7) << 3);
      *(short8*)&es[idx] = *(const short8*)&tmp[q * 8];
    }
    p += __shfl_xor(p, 1);
    p += __shfl_xor(p, 2);
    if ((tid & 3) == 0) {
      float s = p + ksc_t[(size_t)b * E + e0 + r];
      dist_s[r] = 1.f / (1.f + expf(-s));
    }
  }
  __syncthreads();

  int lane = tid & 63, w = tid >> 6;
  int col16 = lane & 15, kg = lane >> 4;
  const int swz = (col16 & 7) << 3;

  // ---- early okb prefetch (fragment layout, fully coalesced b64 loads)
  u16x4 ok4[4][4];
#pragma unroll
  for (int rt = 0; rt < 4; ++rt)
#pragma unroll
    for (int ct = 0; ct < 4; ++ct)
      ok4[rt][ct] = *(const u16x4*)&okb[((((size_t)blk * 4 + w) * 4 + rt) * 4 + ct) * 256 + lane * 4];

  // ---- MFMA: 64x256 tile @ Wv (K=256)
  f32x4 acc[4][4];
#pragma unroll
  for (int rt = 0; rt < 4; ++rt)
#pragma unroll
    for (int ct = 0; ct < 4; ++ct) acc[rt][ct] = (f32x4)(0.f);

#pragma unroll 2
  for (int kb = 0; kb < 8; ++kb) {
    int k0 = kb * 32 + kg * 8;
    short8 a[4];
#pragma unroll
    for (int rt = 0; rt < 4; ++rt)
      a[rt] = *(const short8*)&es[((rt * 16 + col16) * D + k0) ^ swz];
    short8 bv[4];
#pragma unroll
    for (int ct = 0; ct < 4; ++ct)
      bv[ct] = *(const short8*)&Wvfrag[(size_t)(((w * 4 + ct) * 8 + kb) * 64 + lane) * 8];
#pragma unroll
    for (int rt = 0; rt < 4; ++rt)
#pragma unroll
      for (int ct = 0; ct < 4; ++ct)
        acc[rt][ct] = __builtin_amdgcn_mfma_f32_16x16x32_bf16(a[rt], bv[ct], acc[rt][ct], 0, 0, 0);
  }

  // ---- epilogue: pre = acc + oc + ok; gated PReLU blend
#pragma unroll
  for (int rt = 0; rt < 4; ++rt)
#pragma unroll
    for (int ct = 0; ct < 4; ++ct) {
      int n = w * 64 + ct * 16 + col16;
      float ocv = ocs[n], pwv = pws[n];
#pragma unroll
      for (int r = 0; r < 4; ++r) {
        int m = rt * 16 + kg * 4 + r;
        float pre = acc[rt][ct][r] + ocv + bf2f(ok4[rt][ct][r]);
        float pr = pre >= 0.f ? pre : pwv * pre;
        float de = dist_s[m];
        float ev = bf2f(es[(m * D + n) ^ ((m & 7) << 3)]);
        acc[rt][ct][r] = de * pr + (1.f - de) * ev;
      }
    }

  // ---- per-row 1/||new||: 16-col in-wave reduce, then 4 waves via LDS
#pragma unroll
  for (int rt = 0; rt < 4; ++rt)
#pragma unroll
    for (int r = 0; r < 4; ++r) {
      float s = acc[rt][0][r] * acc[rt][0][r] + acc[rt][1][r] * acc[rt][1][r]
              + acc[rt][2][r] * acc[rt][2][r] + acc[rt][3][r] * acc[rt][3][r];
      s += __shfl_xor(s, 1); s += __shfl_xor(s, 2);
      s += __shfl_xor(s, 4); s += __shfl_xor(s, 8);
      if (col16 == 0) rowsum[w][rt * 16 + kg * 4 + r] = s;
    }
  __syncthreads();
  if (tid < MT)
    inv_s[tid] = rsqrtf(rowsum[0][tid] + rowsum[1][tid] + rowsum[2][tid] + rowsum[3][tid]);
  __syncthreads();

  // ---- scale + store (+ joint on LAST)
  size_t obase = ((size_t)b * E + e0) * D;
  float jacc[4] = {0.f, 0.f, 0.f, 0.f};
#pragma unroll
  for (int rt = 0; rt < 4; ++rt)
#pragma unroll
    for (int ct = 0; ct < 4; ++ct) {
      int n = w * 64 + ct * 16 + col16;
#pragma unroll
      for (int r = 0; r < 4; ++r) {
        int m = rt * 16 + kg * 4 + r;
        float val = acc[rt][ct][r] * inv_s[m];
        if (LAST) {
          out_f32[obase + (size_t)m * D + n] = val;
          jacc[ct] += dist_s[m] * val;
        } else {
          out_bf[obase + (size_t)m * D + n] = f2bf(val);
        }
      }
    }
  if (LAST) {
#pragma unroll
    for (int ct = 0; ct < 4; ++ct) {
      float s = jacc[ct];
      s += __shfl_xor(s, 16);
      s += __shfl_xor(s, 32);
      if (kg == 0) atomicAdd(&joint[(size_t)b * D + w * 64 + ct * 16 + col16], s);
    }
  }
}

// ---------------------------------------------------------------------------
extern "C" void kernel_launch(void* const* d_in, const int* in_sizes, int n_in,
                              void* d_out, int out_size, void* d_ws, size_t ws_size,
                              hipStream_t stream) {
  const float* embed    = (const float*)d_in[0];
  const float* pos_w    = (const float*)d_in[1];
  const float* keys     = (const float*)d_in[2];
  const float* entities = (const float*)d_in[3];
  const float* Wk       = (const float*)d_in[4];
  const float* Wv       = (const float*)d_in[5];
  const float* Wc       = (const float*)d_in[6];
  const float* prelu_w  = (const float*)d_in[7];
  const int* sentences  = (const int*)d_in[8];
  const int* lengths    = (const int*)d_in[9];

  float* out_ents  = (float*)d_out;
  float* out_joint = out_ents + (size_t)B * E * D;

  // ws layout (~98 MB; harness provided >=196 MB in round 4's use_kb path)
  float* h   = (float*)d_ws;                               // T*B*D
  float* oc  = h + (size_t)T * B * D;                      // T*B*D
  float* ksc = oc + (size_t)T * B * D;                     // T*B*E
  unsigned short* Wvfrag = (unsigned short*)(ksc + (size_t)T * B * E);  // 64K
  unsigned short* Wkfrag = Wvfrag + (size_t)D * D;         // 64K
  unsigned short* okb    = Wkfrag + (size_t)D * D;         // B*E*D
  unsigned short* ents0  = okb + (size_t)B * E * D;        // B*E*D
  unsigned short* ents1  = ents0 + (size_t)B * E * D;      // B*E*D

  hipMemsetAsync(out_joint, 0, (size_t)B * D * sizeof(float), stream);

  k_h<<<T * B, D, 0, stream>>>(embed, pos_w, sentences, lengths, h);
  k_oc<<<T * B, D, 0, stream>>>(h, Wc, oc);
  k_wt<<<D, D, 0, stream>>>(Wv, Wk, Wvfrag, Wkfrag);
  dim3 grid(NBLK, B);
  k_pre<<<grid, 256, 0, stream>>>(keys, h, Wkfrag, okb, ksc);

  // t = 0: f32 entities -> ents0
  k_step<true, false><<<grid, 256, 0, stream>>>(entities, nullptr, Wvfrag, okb,
      h, oc, ksc, prelu_w, ents0, nullptr, nullptr);
  // t = 1: ents0 -> ents1
  k_step<false, false><<<grid, 256, 0, stream>>>(nullptr, ents0, Wvfrag, okb,
      h + (size_t)1 * B * D, oc + (size_t)1 * B * D, ksc + (size_t)1 * B * E,
      prelu_w, ents1, nullptr, nullptr);
  // t = 2: ents1 -> ents0
  k_step<false, false><<<grid, 256, 0, stream>>>(nullptr, ents1, Wvfrag, okb,
      h + (size_t)2 * B * D, oc + (size_t)2 * B * D, ksc + (size_t)2 * B * E,
      prelu_w, ents0, nullptr, nullptr);
  // t = 3: ents0 -> out (f32) + joint
  k_step<false, true><<<grid, 256, 0, stream>>>(nullptr, ents0, Wvfrag, okb,
      h + (size_t)3 * B * D, oc + (size_t)3 * B * D, ksc + (size_t)3 * B * E,
      prelu_w, nullptr, out_ents, out_joint);

  (void)in_sizes; (void)n_in; (void)out_size; (void)ws_size;
}

// Round 7
// 225.125 us; speedup vs baseline: 4.7612x; 1.2325x over previous
//
#include <hip/hip_runtime.h>
#include <cmath>

// EntNet forward v3: entity rows are independent across the T=4 scan
// (sigmoid gate, row-local update) -> single fused scan kernel.
constexpr int T = 4, B = 64, L = 32, E = 1024, D = 256;
constexpr int MT = 64;            // entity rows per block
constexpr int NBLK = E / MT;      // 16

typedef __attribute__((ext_vector_type(8))) short short8;
typedef __attribute__((ext_vector_type(4))) float f32x4;
typedef __attribute__((ext_vector_type(4))) unsigned short u16x4;

static __device__ __forceinline__ unsigned short f2bf(float x) {
  unsigned int u = __builtin_bit_cast(unsigned int, x);
  unsigned int r = u + 0x7fffu + ((u >> 16) & 1u);   // RNE
  return (unsigned short)(r >> 16);
}
static __device__ __forceinline__ float bf2f(unsigned short s) {
  unsigned int u = ((unsigned int)s) << 16;
  return __builtin_bit_cast(float, u);
}

// ---------------------------------------------------------------------------
// h[t,b,d] = sum_{l < len[t,b]} embed[sent[t,b,l], d] * pos_w[l, d]
__global__ void k_h(const float* __restrict__ embed, const float* __restrict__ pos_w,
                    const int* __restrict__ sentences, const int* __restrict__ lengths,
                    float* __restrict__ h) {
  int tb = blockIdx.x;
  int d  = threadIdx.x;
  const int* sent = sentences + tb * L;
  int len = lengths[tb];
  float acc = 0.f;
  for (int l = 0; l < len; ++l) {
    int tok = sent[l];
    acc += embed[(size_t)tok * D + d] * pos_w[l * D + d];
  }
  h[(size_t)tb * D + d] = acc;
}

// ---------------------------------------------------------------------------
// oc[t,b,f] = sum_d h[t,b,d] * Wc[d,f]
__global__ void k_oc(const float* __restrict__ h, const float* __restrict__ Wc,
                     float* __restrict__ oc) {
  int tb = blockIdx.x;
  int f  = threadIdx.x;
  __shared__ float hs[D];
  hs[f] = h[(size_t)tb * D + f];
  __syncthreads();
  float acc = 0.f;
  for (int d0 = 0; d0 < D; d0 += 4) {
    float4 hv = *(const float4*)&hs[d0];
    acc += hv.x * Wc[(d0 + 0) * D + f] + hv.y * Wc[(d0 + 1) * D + f]
         + hv.z * Wc[(d0 + 2) * D + f] + hv.w * Wc[(d0 + 3) * D + f];
  }
  oc[(size_t)tb * D + f] = acc;
}

// ---------------------------------------------------------------------------
// Fragment-layout weights: idx(n,k) = (((n>>4)*8 + (k>>5))*64 + ((k>>3)&3)*16
// + (n&15))*8 + (k&7). One coalesced b128 per (ct,kb) per wave.
__global__ void k_wt(const float* __restrict__ Wv, const float* __restrict__ Wk,
                     unsigned short* __restrict__ Wvfrag,
                     unsigned short* __restrict__ Wkfrag) {
  int n = blockIdx.x, k = threadIdx.x;
  int idx = (((n >> 4) * 8 + (k >> 5)) * 64 + ((k >> 3) & 3) * 16 + (n & 15)) * 8 + (k & 7);
  Wvfrag[idx] = f2bf(Wv[(size_t)k * D + n]);
  Wkfrag[idx] = f2bf(Wk[(size_t)k * D + n]);
}

// ---------------------------------------------------------------------------
// Fused scan: per 64-row tile, stage keys -> ok=keys@Wk (regs) + ksc[4];
// stage entities; then 4 steps of {MFMA ents@Wv, gated PReLU update, renorm,
// next-dist} entirely on-chip. Final step writes f32 out + joint.
__global__ __launch_bounds__(256) void k_scan(
    const float* __restrict__ entities,
    const float* __restrict__ keys,
    const unsigned short* __restrict__ Wvfrag,
    const unsigned short* __restrict__ Wkfrag,
    const float* __restrict__ h,       // [T][B][D]
    const float* __restrict__ oc,      // [T][B][D]
    const float* __restrict__ prelu_w, // [D]
    float* __restrict__ out_ents,
    float* __restrict__ joint) {
  int b = blockIdx.y, e0 = blockIdx.x * MT;
  int tid = threadIdx.x;
  int lane = tid & 63, w = tid >> 6;
  int col16 = lane & 15, kg = lane >> 4;
  const int aswz = (col16 & 7) << 3;

  __shared__ unsigned short es[MT * D];   // 32 KB swizzled (keys, then ents)
  __shared__ float hs4[T][D];             // 4 KB
  __shared__ float ocs4[T][D];            // 4 KB
  __shared__ float pws[D];
  __shared__ float ksc_s[T][MT];
  __shared__ float dist_s[MT];
  __shared__ float red0[4][MT], red1[4][MT];
  __shared__ float inv_s[MT];

#pragma unroll
  for (int t = 0; t < T; ++t) {
    hs4[t][tid]  = h[((size_t)t * B + b) * D + tid];
    ocs4[t][tid] = oc[((size_t)t * B + b) * D + tid];
  }
  pws[tid] = prelu_w[tid];
  __syncthreads();

  // ---- phase 1: stage keys (f32->bf16 swizzled) + ksc dots for all 4 t
  {
    int r = tid >> 2, c0 = (tid & 3) * 64;
    const float4* src = (const float4*)(keys + ((size_t)b * E + e0 + r) * D + c0);
    float p[T] = {0.f, 0.f, 0.f, 0.f};
    unsigned short tmp[64];
#pragma unroll
    for (int q = 0; q < 16; ++q) {
      float4 v = src[q];
      int c = c0 + q * 4;
#pragma unroll
      for (int t = 0; t < T; ++t)
        p[t] += v.x * hs4[t][c] + v.y * hs4[t][c + 1] + v.z * hs4[t][c + 2] + v.w * hs4[t][c + 3];
      tmp[q * 4 + 0] = f2bf(v.x); tmp[q * 4 + 1] = f2bf(v.y);
      tmp[q * 4 + 2] = f2bf(v.z); tmp[q * 4 + 3] = f2bf(v.w);
    }
#pragma unroll
    for (int q = 0; q < 8; ++q) {
      int idx = (r * D + c0 + q * 8) ^ ((r & 7) << 3);
      *(short8*)&es[idx] = *(const short8*)&tmp[q * 8];
    }
#pragma unroll
    for (int t = 0; t < T; ++t) {
      p[t] += __shfl_xor(p[t], 1);
      p[t] += __shfl_xor(p[t], 2);
    }
    if ((tid & 3) == 0) {
#pragma unroll
      for (int t = 0; t < T; ++t) ksc_s[t][r] = p[t];
    }
  }
  __syncthreads();

  // ---- phase 2: ok = keys @ Wk -> bf16 regs
  u16x4 ok4[4][4];
  {
    f32x4 acc[4][4];
#pragma unroll
    for (int rt = 0; rt < 4; ++rt)
#pragma unroll
      for (int ct = 0; ct < 4; ++ct) acc[rt][ct] = (f32x4)(0.f);
#pragma unroll 2
    for (int kb = 0; kb < 8; ++kb) {
      int k0 = kb * 32 + kg * 8;
      short8 a[4];
#pragma unroll
      for (int rt = 0; rt < 4; ++rt)
        a[rt] = *(const short8*)&es[((rt * 16 + col16) * D + k0) ^ aswz];
      short8 bv[4];
#pragma unroll
      for (int ct = 0; ct < 4; ++ct)
        bv[ct] = *(const short8*)&Wkfrag[(size_t)(((w * 4 + ct) * 8 + kb) * 64 + lane) * 8];
#pragma unroll
      for (int rt = 0; rt < 4; ++rt)
#pragma unroll
        for (int ct = 0; ct < 4; ++ct)
          acc[rt][ct] = __builtin_amdgcn_mfma_f32_16x16x32_bf16(a[rt], bv[ct], acc[rt][ct], 0, 0, 0);
    }
#pragma unroll
    for (int rt = 0; rt < 4; ++rt)
#pragma unroll
      for (int ct = 0; ct < 4; ++ct)
#pragma unroll
        for (int r = 0; r < 4; ++r) ok4[rt][ct][r] = f2bf(acc[rt][ct][r]);
  }
  __syncthreads();   // es (keys) reads complete

  // ---- phase 3: stage entities f32 -> es + dist_0
  {
    int r = tid >> 2, c0 = (tid & 3) * 64;
    const float4* src = (const float4*)(entities + ((size_t)b * E + e0 + r) * D + c0);
    float p = 0.f;
    unsigned short tmp[64];
#pragma unroll
    for (int q = 0; q < 16; ++q) {
      float4 v = src[q];
      int c = c0 + q * 4;
      p += v.x * hs4[0][c] + v.y * hs4[0][c + 1] + v.z * hs4[0][c + 2] + v.w * hs4[0][c + 3];
      tmp[q * 4 + 0] = f2bf(v.x); tmp[q * 4 + 1] = f2bf(v.y);
      tmp[q * 4 + 2] = f2bf(v.z); tmp[q * 4 + 3] = f2bf(v.w);
    }
#pragma unroll
    for (int q = 0; q < 8; ++q) {
      int idx = (r * D + c0 + q * 8) ^ ((r & 7) << 3);
      *(short8*)&es[idx] = *(const short8*)&tmp[q * 8];
    }
    p += __shfl_xor(p, 1);
    p += __shfl_xor(p, 2);
    if ((tid & 3) == 0)
      dist_s[r] = 1.f / (1.f + expf(-(p + ksc_s[0][r])));
  }
  __syncthreads();

  // ---- phase 4: the 4-step scan, fully on-chip
  size_t obase = ((size_t)b * E + e0) * D;
#pragma unroll
  for (int t = 0; t < T; ++t) {
    f32x4 acc[4][4];
#pragma unroll
    for (int rt = 0; rt < 4; ++rt)
#pragma unroll
      for (int ct = 0; ct < 4; ++ct) acc[rt][ct] = (f32x4)(0.f);
#pragma unroll 2
    for (int kb = 0; kb < 8; ++kb) {
      int k0 = kb * 32 + kg * 8;
      short8 a[4];
#pragma unroll
      for (int rt = 0; rt < 4; ++rt)
        a[rt] = *(const short8*)&es[((rt * 16 + col16) * D + k0) ^ aswz];
      short8 bv[4];
#pragma unroll
      for (int ct = 0; ct < 4; ++ct)
        bv[ct] = *(const short8*)&Wvfrag[(size_t)(((w * 4 + ct) * 8 + kb) * 64 + lane) * 8];
#pragma unroll
      for (int rt = 0; rt < 4; ++rt)
#pragma unroll
        for (int ct = 0; ct < 4; ++ct)
          acc[rt][ct] = __builtin_amdgcn_mfma_f32_16x16x32_bf16(a[rt], bv[ct], acc[rt][ct], 0, 0, 0);
    }

    // epilogue: pre = acc + oc + ok; gated PReLU blend with old ents
#pragma unroll
    for (int rt = 0; rt < 4; ++rt)
#pragma unroll
      for (int ct = 0; ct < 4; ++ct) {
        int n = w * 64 + ct * 16 + col16;
        float ocv = ocs4[t][n], pwv = pws[n];
#pragma unroll
        for (int r = 0; r < 4; ++r) {
          int m = rt * 16 + kg * 4 + r;
          float pre = acc[rt][ct][r] + ocv + bf2f(ok4[rt][ct][r]);
          float pr = pre >= 0.f ? pre : pwv * pre;
          float de = dist_s[m];
          float ev = bf2f(es[(m * D + n) ^ ((m & 7) << 3)]);
          acc[rt][ct][r] = de * pr + (1.f - de) * ev;
        }
      }

    // per-row sumsq + next-h dot (fused reductions)
#pragma unroll
    for (int rt = 0; rt < 4; ++rt)
#pragma unroll
      for (int r = 0; r < 4; ++r) {
        float s = acc[rt][0][r] * acc[rt][0][r] + acc[rt][1][r] * acc[rt][1][r]
                + acc[rt][2][r] * acc[rt][2][r] + acc[rt][3][r] * acc[rt][3][r];
        float dn = 0.f;
        if (t < 3) {
#pragma unroll
          for (int ct = 0; ct < 4; ++ct) {
            int n = w * 64 + ct * 16 + col16;
            dn += acc[rt][ct][r] * hs4[t + 1 < T ? t + 1 : 0][n];
          }
        }
        s  += __shfl_xor(s, 1);  s += __shfl_xor(s, 2);
        s  += __shfl_xor(s, 4);  s += __shfl_xor(s, 8);
        if (t < 3) {
          dn += __shfl_xor(dn, 1); dn += __shfl_xor(dn, 2);
          dn += __shfl_xor(dn, 4); dn += __shfl_xor(dn, 8);
        }
        if (col16 == 0) {
          int m = rt * 16 + kg * 4 + r;
          red0[w][m] = s;
          red1[w][m] = dn;
        }
      }
    __syncthreads();
    if (tid < MT) {
      float ss = red0[0][tid] + red0[1][tid] + red0[2][tid] + red0[3][tid];
      float iv = rsqrtf(ss);
      inv_s[tid] = iv;
      if (t < 3) {
        float dd = red1[0][tid] + red1[1][tid] + red1[2][tid] + red1[3][tid];
        dist_s[tid] = 1.f / (1.f + expf(-(iv * dd + ksc_s[t + 1 < T ? t + 1 : 0][tid])));
      }
    }
    __syncthreads();

    // scale + store back (es for next step; global + joint on last)
    if (t < 3) {
#pragma unroll
      for (int rt = 0; rt < 4; ++rt)
#pragma unroll
        for (int ct = 0; ct < 4; ++ct) {
          int n = w * 64 + ct * 16 + col16;
#pragma unroll
          for (int r = 0; r < 4; ++r) {
            int m = rt * 16 + kg * 4 + r;
            es[(m * D + n) ^ ((m & 7) << 3)] = f2bf(acc[rt][ct][r] * inv_s[m]);
          }
        }
    } else {
      float jacc[4] = {0.f, 0.f, 0.f, 0.f};
#pragma unroll
      for (int rt = 0; rt < 4; ++rt)
#pragma unroll
        for (int ct = 0; ct < 4; ++ct) {
          int n = w * 64 + ct * 16 + col16;
#pragma unroll
          for (int r = 0; r < 4; ++r) {
            int m = rt * 16 + kg * 4 + r;
            float val = acc[rt][ct][r] * inv_s[m];
            out_ents[obase + (size_t)m * D + n] = val;
            jacc[ct] += dist_s[m] * val;
          }
        }
#pragma unroll
      for (int ct = 0; ct < 4; ++ct) {
        float s = jacc[ct];
        s += __shfl_xor(s, 16);
        s += __shfl_xor(s, 32);
        if (kg == 0) atomicAdd(&joint[(size_t)b * D + w * 64 + ct * 16 + col16], s);
      }
    }
    __syncthreads();
  }
}

// ---------------------------------------------------------------------------
extern "C" void kernel_launch(void* const* d_in, const int* in_sizes, int n_in,
                              void* d_out, int out_size, void* d_ws, size_t ws_size,
                              hipStream_t stream) {
  const float* embed    = (const float*)d_in[0];
  const float* pos_w    = (const float*)d_in[1];
  const float* keys     = (const float*)d_in[2];
  const float* entities = (const float*)d_in[3];
  const float* Wk       = (const float*)d_in[4];
  const float* Wv       = (const float*)d_in[5];
  const float* Wc       = (const float*)d_in[6];
  const float* prelu_w  = (const float*)d_in[7];
  const int* sentences  = (const int*)d_in[8];
  const int* lengths    = (const int*)d_in[9];

  float* out_ents  = (float*)d_out;
  float* out_joint = out_ents + (size_t)B * E * D;

  // ws: h, oc (f32), Wvfrag/Wkfrag (bf16). ~0.8 MB total.
  float* h  = (float*)d_ws;                                // T*B*D
  float* oc = h + (size_t)T * B * D;                       // T*B*D
  unsigned short* Wvfrag = (unsigned short*)(oc + (size_t)T * B * D);  // D*D
  unsigned short* Wkfrag = Wvfrag + (size_t)D * D;         // D*D

  hipMemsetAsync(out_joint, 0, (size_t)B * D * sizeof(float), stream);

  k_h<<<T * B, D, 0, stream>>>(embed, pos_w, sentences, lengths, h);
  k_oc<<<T * B, D, 0, stream>>>(h, Wc, oc);
  k_wt<<<D, D, 0, stream>>>(Wv, Wk, Wvfrag, Wkfrag);

  dim3 grid(NBLK, B);
  k_scan<<<grid, 256, 0, stream>>>(entities, keys, Wvfrag, Wkfrag,
                                   h, oc, prelu_w, out_ents, out_joint);

  (void)in_sizes; (void)n_in; (void)out_size; (void)ws_size;
}